// Round 1
// baseline (1037.270 us; speedup 1.0000x reference)
//
#include <hip/hip_runtime.h>
#include <math.h>

#define Bq 4
#define Lq 2048
#define DMODEL 512
#define NH 8
#define DKH 64
#define ROWS (Bq*Lq)   // 8192

// ---------------- GEMM: C[M][512] = A[M][512] @ W[512][512] + bias[512] ----------------
// BM=BN=64, BK=16, 256 threads, 4x4 micro-tile per thread, float4 LDS reads.
__global__ __launch_bounds__(256) void gemm_bias_kernel(
    const float* __restrict__ A, const float* __restrict__ W,
    const float* __restrict__ bias, float* __restrict__ C)
{
    __shared__ __align__(16) float As[16 * 64];   // As[k][m] (transposed A tile)
    __shared__ float4 Ws4[16 * 16];               // Ws[k][n/4]

    const int tid = threadIdx.x;
    const int tx = tid & 15, ty = tid >> 4;
    const int n0 = blockIdx.x * 64;
    const int m0 = blockIdx.y * 64;

    const int ra = tid >> 2, ca = tid & 3;        // A staging: row 0..63, col4 0..3
    const int rw = tid >> 4, cw = tid & 15;       // W staging: row 0..15, col4 0..15

    float acc[4][4] = {};

    for (int k0 = 0; k0 < 512; k0 += 16) {
        float4 av = *(const float4*)(A + (size_t)(m0 + ra) * 512 + k0 + ca * 4);
        float4 wv = *(const float4*)(W + (size_t)(k0 + rw) * 512 + n0 + cw * 4);
        __syncthreads();   // previous iteration's compute done before overwrite
        As[(ca * 4 + 0) * 64 + ra] = av.x;
        As[(ca * 4 + 1) * 64 + ra] = av.y;
        As[(ca * 4 + 2) * 64 + ra] = av.z;
        As[(ca * 4 + 3) * 64 + ra] = av.w;
        Ws4[rw * 16 + cw] = wv;
        __syncthreads();
        #pragma unroll
        for (int kk = 0; kk < 16; ++kk) {
            float4 a4 = ((const float4*)As)[kk * 16 + ty];
            float4 w4 = Ws4[kk * 16 + tx];
            acc[0][0] += a4.x * w4.x; acc[0][1] += a4.x * w4.y; acc[0][2] += a4.x * w4.z; acc[0][3] += a4.x * w4.w;
            acc[1][0] += a4.y * w4.x; acc[1][1] += a4.y * w4.y; acc[1][2] += a4.y * w4.z; acc[1][3] += a4.y * w4.w;
            acc[2][0] += a4.z * w4.x; acc[2][1] += a4.z * w4.y; acc[2][2] += a4.z * w4.z; acc[2][3] += a4.z * w4.w;
            acc[3][0] += a4.w * w4.x; acc[3][1] += a4.w * w4.y; acc[3][2] += a4.w * w4.z; acc[3][3] += a4.w * w4.w;
        }
    }

    float4 bv = *(const float4*)(bias + n0 + tx * 4);
    #pragma unroll
    for (int i = 0; i < 4; ++i) {
        float4 cv;
        cv.x = acc[i][0] + bv.x;
        cv.y = acc[i][1] + bv.y;
        cv.z = acc[i][2] + bv.z;
        cv.w = acc[i][3] + bv.w;
        *(float4*)(C + (size_t)(m0 + ty * 4 + i) * 512 + n0 + tx * 4) = cv;
    }
}

// ---------------- Attention ----------------
// Grid: (32 bh, 16). Block 256 threads = 128 q-rows x 2 KV-halves (1024 keys each).
// Softmax without max-subtraction (scores bounded ~|12|), masked keys get p=0.
__global__ __launch_bounds__(256) void attn_kernel(
    const float* __restrict__ Qf, const float* __restrict__ Kf,
    const float* __restrict__ Vf, const int* __restrict__ mask,
    float* __restrict__ XS)
{
    __shared__ float4 Ks4[128 * 16];   // 128 staged K rows (64 per half) x 64 floats
    __shared__ float4 Vs4[128 * 16];
    __shared__ int    mskS[128];
    __shared__ float  lred[128];

    const int tid = threadIdx.x;
    const int bh = blockIdx.x;
    const int b = bh >> 3, h = bh & 7;
    const int half = tid >> 7;            // 0: keys [0,1024), 1: keys [1024,2048)
    const int r = tid & 127;              // row within block
    const int row = blockIdx.y * 128 + r;

    const size_t qoff = ((size_t)(b * Lq + row)) * 512 + h * 64;

    float q[64], o[64] = {};
    {
        const float4* qg = (const float4*)(Qf + qoff);
        #pragma unroll
        for (int i = 0; i < 16; ++i) {
            float4 v = qg[i];
            q[4*i+0] = v.x; q[4*i+1] = v.y; q[4*i+2] = v.z; q[4*i+3] = v.w;
        }
    }
    float l = 0.f;

    for (int t = 0; t < 16; ++t) {
        __syncthreads();
        for (int u = tid; u < 128 * 16; u += 256) {
            int rr = u >> 4, c4 = u & 15;
            int kv = ((rr >> 6) << 10) + t * 64 + (rr & 63);
            size_t g = ((size_t)(b * Lq + kv)) * 512 + h * 64 + c4 * 4;
            Ks4[u] = *(const float4*)(Kf + g);
            Vs4[u] = *(const float4*)(Vf + g);
        }
        if (tid < 128) {
            int kv = ((tid >> 6) << 10) + t * 64 + (tid & 63);
            mskS[tid] = mask[b * Lq + kv];
        }
        __syncthreads();

        for (int j = 0; j < 64; ++j) {
            const float4* kr = &Ks4[(half * 64 + j) * 16];
            float s0 = 0.f, s1 = 0.f, s2 = 0.f, s3 = 0.f;
            #pragma unroll
            for (int d4 = 0; d4 < 16; ++d4) {
                float4 kk = kr[d4];
                s0 += q[4*d4+0] * kk.x; s1 += q[4*d4+1] * kk.y;
                s2 += q[4*d4+2] * kk.z; s3 += q[4*d4+3] * kk.w;
            }
            float s = ((s0 + s1) + (s2 + s3)) * 0.125f;
            // mask value 0 => excluded (reference: where(mask==0, min, .))
            float pj = mskS[half * 64 + j] ? __expf(s) : 0.f;
            l += pj;
            const float4* vr = &Vs4[(half * 64 + j) * 16];
            #pragma unroll
            for (int d4 = 0; d4 < 16; ++d4) {
                float4 vv = vr[d4];
                o[4*d4+0] += pj * vv.x; o[4*d4+1] += pj * vv.y;
                o[4*d4+2] += pj * vv.z; o[4*d4+3] += pj * vv.w;
            }
        }
    }

    // merge the two KV-halves: half1 -> LDS, half0 adds and writes
    __syncthreads();
    float* obuf = (float*)Ks4;   // reuse: obuf[d][r] layout (conflict-free), 64*128 floats = 32KB
    if (half == 1) {
        #pragma unroll
        for (int d = 0; d < 64; ++d) obuf[d * 128 + r] = o[d];
        lred[r] = l;
    }
    __syncthreads();
    if (half == 0) {
        l += lred[r];
        float inv = (l > 0.f) ? 1.f / l : 0.f;   // all-masked row -> exact 0 like reference
        float4* og = (float4*)(XS + qoff);
        #pragma unroll
        for (int i = 0; i < 16; ++i) {
            float4 v;
            v.x = (o[4*i+0] + obuf[(4*i+0) * 128 + r]) * inv;
            v.y = (o[4*i+1] + obuf[(4*i+1) * 128 + r]) * inv;
            v.z = (o[4*i+2] + obuf[(4*i+2) * 128 + r]) * inv;
            v.w = (o[4*i+3] + obuf[(4*i+3) * 128 + r]) * inv;
            og[i] = v;
        }
    }
}

extern "C" void kernel_launch(void* const* d_in, const int* in_sizes, int n_in,
                              void* d_out, int out_size, void* d_ws, size_t ws_size,
                              hipStream_t stream) {
    const float* query = (const float*)d_in[0];
    const float* key   = (const float*)d_in[1];
    const float* value = (const float*)d_in[2];
    const int*   mask  = (const int*)d_in[3];
    const float* Wq = (const float*)d_in[4];
    const float* bq = (const float*)d_in[5];
    const float* Wk = (const float*)d_in[6];
    const float* bk = (const float*)d_in[7];
    const float* Wv = (const float*)d_in[8];
    const float* bv = (const float*)d_in[9];
    const float* Wo = (const float*)d_in[10];
    const float* bo = (const float*)d_in[11];

    float* ws = (float*)d_ws;
    const size_t PLANE = (size_t)ROWS * DMODEL;   // 4M floats = 16 MB
    float* Qf = ws;
    float* Kf = ws + PLANE;
    float* Vf = ws + 2 * PLANE;
    float* XS = ws + 3 * PLANE;

    dim3 gg(DMODEL / 64, ROWS / 64);   // (8, 128)
    dim3 bb(256);
    gemm_bias_kernel<<<gg, bb, 0, stream>>>(query, Wq, bq, Qf);
    gemm_bias_kernel<<<gg, bb, 0, stream>>>(key,   Wk, bk, Kf);
    gemm_bias_kernel<<<gg, bb, 0, stream>>>(value, Wv, bv, Vf);

    attn_kernel<<<dim3(Bq * NH, Lq / 128), 256, 0, stream>>>(Qf, Kf, Vf, mask, XS);

    gemm_bias_kernel<<<gg, bb, 0, stream>>>(XS, Wo, bo, (float*)d_out);
}

// Round 2
// 520.091 us; speedup vs baseline: 1.9944x; 1.9944x over previous
//
#include <hip/hip_runtime.h>
#include <math.h>

#define Bq 4
#define Lq 2048
#define DMODEL 512
#define NH 8
#define ROWS (Bq*Lq)   // 8192

typedef __attribute__((ext_vector_type(8))) __bf16 bf16x8;
typedef __attribute__((ext_vector_type(4))) float f32x4;
#define MFMA16(a,b,c) __builtin_amdgcn_mfma_f32_16x16x32_bf16(a,b,c,0,0,0)

// truncation split: x = hi + lo (+ ~2^-16 residual). hi = trunc-to-bf16, lo = bf16(x - hi_f32).
__device__ __forceinline__ void splitbf(float x, ushort& h, ushort& l) {
    unsigned u = __float_as_uint(x);
    h = (ushort)(u >> 16);
    float hf = __uint_as_float(u & 0xffff0000u);
    l = (ushort)(__float_as_uint(x - hf) >> 16);
}

// ---------------- fp32 GEMM: C[M][512] = A[M][512] @ W[512][512] + bias ----------------
__global__ __launch_bounds__(256) void gemm_bias_kernel(
    const float* __restrict__ A, const float* __restrict__ W,
    const float* __restrict__ bias, float* __restrict__ C)
{
    __shared__ __align__(16) float As[16 * 64];
    __shared__ float4 Ws4[16 * 16];

    const int tid = threadIdx.x;
    const int tx = tid & 15, ty = tid >> 4;
    const int n0 = blockIdx.x * 64;
    const int m0 = blockIdx.y * 64;
    const int ra = tid >> 2, ca = tid & 3;
    const int rw = tid >> 4, cw = tid & 15;

    float acc[4][4] = {};
    for (int k0 = 0; k0 < 512; k0 += 16) {
        float4 av = *(const float4*)(A + (size_t)(m0 + ra) * 512 + k0 + ca * 4);
        float4 wv = *(const float4*)(W + (size_t)(k0 + rw) * 512 + n0 + cw * 4);
        __syncthreads();
        As[(ca * 4 + 0) * 64 + ra] = av.x;
        As[(ca * 4 + 1) * 64 + ra] = av.y;
        As[(ca * 4 + 2) * 64 + ra] = av.z;
        As[(ca * 4 + 3) * 64 + ra] = av.w;
        Ws4[rw * 16 + cw] = wv;
        __syncthreads();
        #pragma unroll
        for (int kk = 0; kk < 16; ++kk) {
            float4 a4 = ((const float4*)As)[kk * 16 + ty];
            float4 w4 = Ws4[kk * 16 + tx];
            acc[0][0] += a4.x * w4.x; acc[0][1] += a4.x * w4.y; acc[0][2] += a4.x * w4.z; acc[0][3] += a4.x * w4.w;
            acc[1][0] += a4.y * w4.x; acc[1][1] += a4.y * w4.y; acc[1][2] += a4.y * w4.z; acc[1][3] += a4.y * w4.w;
            acc[2][0] += a4.z * w4.x; acc[2][1] += a4.z * w4.y; acc[2][2] += a4.z * w4.z; acc[2][3] += a4.z * w4.w;
            acc[3][0] += a4.w * w4.x; acc[3][1] += a4.w * w4.y; acc[3][2] += a4.w * w4.z; acc[3][3] += a4.w * w4.w;
        }
    }

    float4 bv = *(const float4*)(bias + n0 + tx * 4);
    #pragma unroll
    for (int i = 0; i < 4; ++i) {
        float4 cv;
        cv.x = acc[i][0] + bv.x; cv.y = acc[i][1] + bv.y;
        cv.z = acc[i][2] + bv.z; cv.w = acc[i][3] + bv.w;
        *(float4*)(C + (size_t)(m0 + ty * 4 + i) * 512 + n0 + tx * 4) = cv;
    }
}

// ---------------- same GEMM, epilogue writes split-bf16 planes [bh][row][64] ----------------
__global__ __launch_bounds__(256) void gemm_bias_split_kernel(
    const float* __restrict__ A, const float* __restrict__ W,
    const float* __restrict__ bias, ushort* __restrict__ Ph, ushort* __restrict__ Pl)
{
    __shared__ __align__(16) float As[16 * 64];
    __shared__ float4 Ws4[16 * 16];

    const int tid = threadIdx.x;
    const int tx = tid & 15, ty = tid >> 4;
    const int n0 = blockIdx.x * 64;
    const int m0 = blockIdx.y * 64;
    const int ra = tid >> 2, ca = tid & 3;
    const int rw = tid >> 4, cw = tid & 15;

    float acc[4][4] = {};
    for (int k0 = 0; k0 < 512; k0 += 16) {
        float4 av = *(const float4*)(A + (size_t)(m0 + ra) * 512 + k0 + ca * 4);
        float4 wv = *(const float4*)(W + (size_t)(k0 + rw) * 512 + n0 + cw * 4);
        __syncthreads();
        As[(ca * 4 + 0) * 64 + ra] = av.x;
        As[(ca * 4 + 1) * 64 + ra] = av.y;
        As[(ca * 4 + 2) * 64 + ra] = av.z;
        As[(ca * 4 + 3) * 64 + ra] = av.w;
        Ws4[rw * 16 + cw] = wv;
        __syncthreads();
        #pragma unroll
        for (int kk = 0; kk < 16; ++kk) {
            float4 a4 = ((const float4*)As)[kk * 16 + ty];
            float4 w4 = Ws4[kk * 16 + tx];
            acc[0][0] += a4.x * w4.x; acc[0][1] += a4.x * w4.y; acc[0][2] += a4.x * w4.z; acc[0][3] += a4.x * w4.w;
            acc[1][0] += a4.y * w4.x; acc[1][1] += a4.y * w4.y; acc[1][2] += a4.y * w4.z; acc[1][3] += a4.y * w4.w;
            acc[2][0] += a4.z * w4.x; acc[2][1] += a4.z * w4.y; acc[2][2] += a4.z * w4.z; acc[2][3] += a4.z * w4.w;
            acc[3][0] += a4.w * w4.x; acc[3][1] += a4.w * w4.y; acc[3][2] += a4.w * w4.z; acc[3][3] += a4.w * w4.w;
        }
    }

    float4 bv = *(const float4*)(bias + n0 + tx * 4);
    const int h = blockIdx.x;     // n-tile == one head (64 cols)
    const int d0 = tx * 4;
    #pragma unroll
    for (int i = 0; i < 4; ++i) {
        int rowg = m0 + ty * 4 + i;
        int b = rowg >> 11, r = rowg & 2047;
        float c0 = acc[i][0] + bv.x, c1 = acc[i][1] + bv.y;
        float c2 = acc[i][2] + bv.z, c3 = acc[i][3] + bv.w;
        ushort4 hv, lv;
        splitbf(c0, hv.x, lv.x); splitbf(c1, hv.y, lv.y);
        splitbf(c2, hv.z, lv.z); splitbf(c3, hv.w, lv.w);
        size_t off = ((size_t)(b * 8 + h) * 2048 + r) * 64 + d0;
        *(ushort4*)(Ph + off) = hv;
        *(ushort4*)(Pl + off) = lv;
    }
}

// ---------------- Vf fp32 [8192][512] -> VhT/VlT bf16 [bh][d][key] ----------------
__global__ __launch_bounds__(256) void vtrans_kernel(
    const float* __restrict__ Vf, ushort* __restrict__ VhT, ushort* __restrict__ VlT)
{
    __shared__ float T[64][65];
    const int bh = blockIdx.x, b = bh >> 3, h = bh & 7;
    const int key0 = blockIdx.y * 64;
    const int tid = threadIdx.x;

    #pragma unroll
    for (int i = 0; i < 4; ++i) {
        int u = tid + i * 256;               // 0..1023
        int row = u >> 4, cc = (u & 15) * 4;
        float4 v = *(const float4*)(Vf + ((size_t)(b * 2048 + key0 + row)) * 512 + h * 64 + cc);
        T[row][cc + 0] = v.x; T[row][cc + 1] = v.y; T[row][cc + 2] = v.z; T[row][cc + 3] = v.w;
    }
    __syncthreads();
    #pragma unroll
    for (int i = 0; i < 2; ++i) {
        int u = tid + i * 256;               // 0..511
        int d = u >> 3, c8 = (u & 7) * 8;
        ushort hs[8], ls[8];
        #pragma unroll
        for (int j = 0; j < 8; ++j) splitbf(T[c8 + j][d], hs[j], ls[j]);
        uint4 wh, wl;
        wh.x = hs[0] | ((unsigned)hs[1] << 16); wh.y = hs[2] | ((unsigned)hs[3] << 16);
        wh.z = hs[4] | ((unsigned)hs[5] << 16); wh.w = hs[6] | ((unsigned)hs[7] << 16);
        wl.x = ls[0] | ((unsigned)ls[1] << 16); wl.y = ls[2] | ((unsigned)ls[3] << 16);
        wl.z = ls[4] | ((unsigned)ls[5] << 16); wl.w = ls[6] | ((unsigned)ls[7] << 16);
        size_t off = ((size_t)bh * 64 + d) * 2048 + key0 + c8;
        *(uint4*)(VhT + off) = wh;
        *(uint4*)(VlT + off) = wl;
    }
}

// ---------------- Flash-style split-bf16 MFMA attention ----------------
// Block: 64 q-rows (4 waves x 16), kv-tiles of 64 keys. Grid (32 bh, 32 q-tiles).
#define LDK 72   // padded LDS row length (shorts): 2-way max bank aliasing (free)
__global__ __launch_bounds__(256) void attn_mfma_kernel(
    const ushort* __restrict__ Qh, const ushort* __restrict__ Ql,
    const ushort* __restrict__ Kh, const ushort* __restrict__ Kl,
    const ushort* __restrict__ VhT, const ushort* __restrict__ VlT,
    const int* __restrict__ mask, float* __restrict__ XS)
{
    __shared__ ushort Ks[2][64 * LDK];       // [hi/lo][key][d]
    __shared__ ushort Vs[2][64 * LDK];       // [hi/lo][d][key]
    __shared__ ushort Ps[4][2][16 * LDK];    // per-wave P round-trip [hi/lo][row][key]

    const int tid = threadIdx.x;
    const int wave = tid >> 6, lane = tid & 63;
    const int l15 = lane & 15, quad = lane >> 4;
    const int bh = blockIdx.x, b = bh >> 3, h = bh & 7;
    const int q0 = blockIdx.y * 64;

    // Q fragments (A-operand: A[m=lane&15][k=quad*8+j]) straight from global, kept all loop
    bf16x8 qh[2], ql[2];
    {
        size_t qb = ((size_t)bh * 2048 + q0 + wave * 16 + l15) * 64 + quad * 8;
        qh[0] = *(const bf16x8*)(Qh + qb);
        qh[1] = *(const bf16x8*)(Qh + qb + 32);
        ql[0] = *(const bf16x8*)(Ql + qb);
        ql[1] = *(const bf16x8*)(Ql + qb + 32);
    }

    const f32x4 z = {0.f, 0.f, 0.f, 0.f};
    f32x4 oacc[4] = {z, z, z, z};
    float lacc[4] = {0.f, 0.f, 0.f, 0.f};

    // staging: each thread copies 8 x 16B chunks (2 per plane)
    const int r0 = tid >> 3;                 // 0..31
    const int c8 = (tid & 7) * 8;
    const ushort* kh_p = Kh + ((size_t)bh * 2048 + r0) * 64 + c8;
    const ushort* kl_p = Kl + ((size_t)bh * 2048 + r0) * 64 + c8;
    const ushort* vh_p = VhT + ((size_t)bh * 64 + r0) * 2048 + c8;
    const ushort* vl_p = VlT + ((size_t)bh * 64 + r0) * 2048 + c8;
    ushort* dK0a = &Ks[0][r0 * LDK + c8];  ushort* dK0b = &Ks[0][(r0 + 32) * LDK + c8];
    ushort* dK1a = &Ks[1][r0 * LDK + c8];  ushort* dK1b = &Ks[1][(r0 + 32) * LDK + c8];
    ushort* dV0a = &Vs[0][r0 * LDK + c8];  ushort* dV0b = &Vs[0][(r0 + 32) * LDK + c8];
    ushort* dV1a = &Vs[1][r0 * LDK + c8];  ushort* dV1b = &Vs[1][(r0 + 32) * LDK + c8];

    const int kfb = l15 * LDK + quad * 8;    // B-fragment base offset (shorts)
    ushort* pw_h = &Ps[wave][0][quad * 4 * LDK + l15];
    ushort* pw_l = &Ps[wave][1][quad * 4 * LDK + l15];
    const ushort* pr_h = &Ps[wave][0][l15 * LDK + quad * 8];
    const ushort* pr_l = &Ps[wave][1][l15 * LDK + quad * 8];

    for (int t = 0; t < 32; ++t) {
        const int key0 = t * 64;
        __syncthreads();
        *(uint4*)dK0a = *(const uint4*)(kh_p + (size_t)key0 * 64);
        *(uint4*)dK0b = *(const uint4*)(kh_p + (size_t)key0 * 64 + 32 * 64);
        *(uint4*)dK1a = *(const uint4*)(kl_p + (size_t)key0 * 64);
        *(uint4*)dK1b = *(const uint4*)(kl_p + (size_t)key0 * 64 + 32 * 64);
        *(uint4*)dV0a = *(const uint4*)(vh_p + key0);
        *(uint4*)dV0b = *(const uint4*)(vh_p + key0 + 32 * 2048);
        *(uint4*)dV1a = *(const uint4*)(vl_p + key0);
        *(uint4*)dV1b = *(const uint4*)(vl_p + key0 + 32 * 2048);
        __syncthreads();

        float bias[4];
        #pragma unroll
        for (int nt = 0; nt < 4; ++nt)
            bias[nt] = mask[b * 2048 + key0 + nt * 16 + l15] ? 0.f : -1e30f;

        // S = Q K^T  (three split terms, fp32 acc)
        f32x4 s[4];
        #pragma unroll
        for (int nt = 0; nt < 4; ++nt) {
            bf16x8 kh0 = *(const bf16x8*)&Ks[0][kfb + nt * 16 * LDK];
            bf16x8 kh1 = *(const bf16x8*)&Ks[0][kfb + nt * 16 * LDK + 32];
            bf16x8 kl0 = *(const bf16x8*)&Ks[1][kfb + nt * 16 * LDK];
            bf16x8 kl1 = *(const bf16x8*)&Ks[1][kfb + nt * 16 * LDK + 32];
            f32x4 a = z;
            a = MFMA16(qh[0], kh0, a);
            a = MFMA16(qh[1], kh1, a);
            a = MFMA16(ql[0], kh0, a);
            a = MFMA16(ql[1], kh1, a);
            a = MFMA16(qh[0], kl0, a);
            a = MFMA16(qh[1], kl1, a);
            s[nt] = a;
        }

        // softmax piece: p = exp(s/8 + bias), accumulate l, split-write P (C-layout -> [row][key])
        #pragma unroll
        for (int nt = 0; nt < 4; ++nt) {
            #pragma unroll
            for (int r = 0; r < 4; ++r) {
                float sv = s[nt][r] * 0.125f + bias[nt];
                float p = __expf(sv);
                lacc[r] += p;
                unsigned u = __float_as_uint(p);
                float hf = __uint_as_float(u & 0xffff0000u);
                pw_h[r * LDK + nt * 16] = (ushort)(u >> 16);
                pw_l[r * LDK + nt * 16] = (ushort)(__float_as_uint(p - hf) >> 16);
            }
        }

        // O += P V  (P via per-wave LDS; V^T as B-operand)
        #pragma unroll
        for (int ks = 0; ks < 2; ++ks) {
            bf16x8 ph = *(const bf16x8*)(pr_h + ks * 32);
            bf16x8 pl = *(const bf16x8*)(pr_l + ks * 32);
            #pragma unroll
            for (int nt = 0; nt < 4; ++nt) {
                bf16x8 vh = *(const bf16x8*)&Vs[0][kfb + nt * 16 * LDK + ks * 32];
                bf16x8 vl = *(const bf16x8*)&Vs[1][kfb + nt * 16 * LDK + ks * 32];
                oacc[nt] = MFMA16(ph, vh, oacc[nt]);
                oacc[nt] = MFMA16(pl, vh, oacc[nt]);
                oacc[nt] = MFMA16(ph, vl, oacc[nt]);
            }
        }
    }

    // reduce l across the 16 lanes sharing each row, then normalize + write
    #pragma unroll
    for (int r = 0; r < 4; ++r) {
        float v = lacc[r];
        v += __shfl_xor(v, 1); v += __shfl_xor(v, 2);
        v += __shfl_xor(v, 4); v += __shfl_xor(v, 8);
        lacc[r] = (v > 0.f) ? 1.f / v : 0.f;
    }
    const size_t rb = (size_t)b * 2048 + q0 + wave * 16 + quad * 4;
    #pragma unroll
    for (int r = 0; r < 4; ++r) {
        float* rowp = XS + (rb + r) * 512 + h * 64 + l15;
        #pragma unroll
        for (int nt = 0; nt < 4; ++nt)
            rowp[nt * 16] = oacc[nt][r] * lacc[r];
    }
}

extern "C" void kernel_launch(void* const* d_in, const int* in_sizes, int n_in,
                              void* d_out, int out_size, void* d_ws, size_t ws_size,
                              hipStream_t stream) {
    const float* query = (const float*)d_in[0];
    const float* key   = (const float*)d_in[1];
    const float* value = (const float*)d_in[2];
    const int*   mask  = (const int*)d_in[3];
    const float* Wq = (const float*)d_in[4];
    const float* bq = (const float*)d_in[5];
    const float* Wk = (const float*)d_in[6];
    const float* bk = (const float*)d_in[7];
    const float* Wv = (const float*)d_in[8];
    const float* bv = (const float*)d_in[9];
    const float* Wo = (const float*)d_in[10];
    const float* bo = (const float*)d_in[11];

    char* w = (char*)d_ws;
    const size_t PL = (size_t)8 << 20;          // 8 MB per bf16 plane
    ushort* Qh  = (ushort*)(w + 0 * PL);
    ushort* Ql  = (ushort*)(w + 1 * PL);
    ushort* Kh  = (ushort*)(w + 2 * PL);
    ushort* Kl  = (ushort*)(w + 3 * PL);
    ushort* VhT = (ushort*)(w + 4 * PL);
    ushort* VlT = (ushort*)(w + 5 * PL);
    float*  Vf  = (float*)(w + 6 * PL);          // 16 MB; reused as XS after vtrans
    float*  XS  = Vf;

    dim3 gg(DMODEL / 64, ROWS / 64);   // (8, 128)
    gemm_bias_split_kernel<<<gg, 256, 0, stream>>>(query, Wq, bq, Qh, Ql);
    gemm_bias_split_kernel<<<gg, 256, 0, stream>>>(key,   Wk, bk, Kh, Kl);
    gemm_bias_kernel<<<gg, 256, 0, stream>>>(value, Wv, bv, Vf);
    vtrans_kernel<<<dim3(32, 32), 256, 0, stream>>>(Vf, VhT, VlT);
    attn_mfma_kernel<<<dim3(32, 32), 256, 0, stream>>>(Qh, Ql, Kh, Kl, VhT, VlT, mask, XS);
    gemm_bias_kernel<<<gg, 256, 0, stream>>>(XS, Wo, bo, (float*)d_out);
}

// Round 3
// 390.052 us; speedup vs baseline: 2.6593x; 1.3334x over previous
//
#include <hip/hip_runtime.h>
#include <math.h>

#define Bq 4
#define Lq 2048
#define NH 8
#define ROWS 8192
#define LDP 68   // P-buffer row stride in uints

typedef __attribute__((ext_vector_type(8))) __bf16 bf16x8;
typedef __attribute__((ext_vector_type(4))) float f32x4;
#define MFMA16(a,b,c) __builtin_amdgcn_mfma_f32_16x16x32_bf16(a,b,c,0,0,0)

__device__ __forceinline__ void async16(const void* g, void* l) {
    __builtin_amdgcn_global_load_lds(
        (const __attribute__((address_space(1))) unsigned int*)g,
        (__attribute__((address_space(3))) unsigned int*)l, 16, 0, 0);
}

// truncation split: x = hi + lo (+ ~2^-16 rel residual)
__device__ __forceinline__ void splitbf(float x, ushort& h, ushort& l) {
    unsigned u = __float_as_uint(x);
    h = (ushort)(u >> 16);
    float hf = __uint_as_float(u & 0xffff0000u);
    l = (ushort)(__float_as_uint(x - hf) >> 16);
}

// ---------------- W [512k][512n] fp32 -> WhT/WlT [n][k] bf16 planes ----------------
__global__ __launch_bounds__(256) void wsplit_kernel(
    const float* __restrict__ W, ushort* __restrict__ WhT, ushort* __restrict__ WlT)
{
    __shared__ float T[64][65];
    const int k0 = blockIdx.x * 64, n0 = blockIdx.y * 64;
    const int tid = threadIdx.x;
    #pragma unroll
    for (int i = 0; i < 4; ++i) {
        int u = tid + i * 256;
        int row = u >> 4, c4 = (u & 15) * 4;
        float4 v = *(const float4*)(W + (size_t)(k0 + row) * 512 + n0 + c4);
        T[row][c4 + 0] = v.x; T[row][c4 + 1] = v.y; T[row][c4 + 2] = v.z; T[row][c4 + 3] = v.w;
    }
    __syncthreads();
    #pragma unroll
    for (int i = 0; i < 2; ++i) {
        int u = tid + i * 256;
        int d = u >> 3, c8 = (u & 7) * 8;
        ushort hs[8], ls[8];
        #pragma unroll
        for (int j = 0; j < 8; ++j) splitbf(T[c8 + j][d], hs[j], ls[j]);
        uint4 wh, wl;
        wh.x = hs[0] | ((unsigned)hs[1] << 16); wh.y = hs[2] | ((unsigned)hs[3] << 16);
        wh.z = hs[4] | ((unsigned)hs[5] << 16); wh.w = hs[6] | ((unsigned)hs[7] << 16);
        wl.x = ls[0] | ((unsigned)ls[1] << 16); wl.y = ls[2] | ((unsigned)ls[3] << 16);
        wl.z = ls[4] | ((unsigned)ls[5] << 16); wl.w = ls[6] | ((unsigned)ls[7] << 16);
        size_t off = (size_t)(n0 + d) * 512 + k0 + c8;
        *(uint4*)(WhT + off) = wh;
        *(uint4*)(WlT + off) = wl;
    }
}

// ---------------- split-bf16 MFMA GEMM: C[M][512] = A[M][512] @ W + bias ----------------
// 128x128 tile, BK=32, 3-term split. mode 0: fp32 C; mode 1: split planes [bh][row][64].
__global__ __launch_bounds__(256) void gemm_split_kernel(
    const float* __restrict__ A, const ushort* __restrict__ BhT, const ushort* __restrict__ BlT,
    const float* __restrict__ bias, int mode,
    float* __restrict__ Cf, ushort* __restrict__ Ph, ushort* __restrict__ Pl)
{
    __shared__ ushort Ah[128 * 40], Al[128 * 40], Bh[128 * 40], Bl[128 * 40];
    const int tid = threadIdx.x;
    const int wave = tid >> 6, lane = tid & 63;
    const int l15 = lane & 15, quad = lane >> 4;
    const int m0 = blockIdx.x * 128, n0 = blockIdx.y * 128;
    const int wm = (wave >> 1) * 64, wn = (wave & 1) * 64;

    const int am = tid >> 3, ak4 = (tid & 7) * 4;     // A staging
    const int bn = tid >> 2, bk8 = (tid & 3) * 8;     // B staging

    f32x4 acc[4][4];
    #pragma unroll
    for (int i = 0; i < 4; ++i)
        #pragma unroll
        for (int j = 0; j < 4; ++j) acc[i][j] = (f32x4){0.f, 0.f, 0.f, 0.f};

    float4 av[4]; uint4 bh4[2], bl4[2];
    #pragma unroll
    for (int i = 0; i < 4; ++i)
        av[i] = *(const float4*)(A + (size_t)(m0 + am + 32 * i) * 512 + ak4);
    #pragma unroll
    for (int i = 0; i < 2; ++i) {
        bh4[i] = *(const uint4*)(BhT + (size_t)(n0 + bn + 64 * i) * 512 + bk8);
        bl4[i] = *(const uint4*)(BlT + (size_t)(n0 + bn + 64 * i) * 512 + bk8);
    }

    for (int k0 = 0; k0 < 512; k0 += 32) {
        __syncthreads();
        #pragma unroll
        for (int i = 0; i < 4; ++i) {
            ushort4 h4, l4;
            splitbf(av[i].x, h4.x, l4.x); splitbf(av[i].y, h4.y, l4.y);
            splitbf(av[i].z, h4.z, l4.z); splitbf(av[i].w, h4.w, l4.w);
            *(ushort4*)&Ah[(am + 32 * i) * 40 + ak4] = h4;
            *(ushort4*)&Al[(am + 32 * i) * 40 + ak4] = l4;
        }
        #pragma unroll
        for (int i = 0; i < 2; ++i) {
            *(uint4*)&Bh[(bn + 64 * i) * 40 + bk8] = bh4[i];
            *(uint4*)&Bl[(bn + 64 * i) * 40 + bk8] = bl4[i];
        }
        __syncthreads();
        if (k0 < 480) {
            int kn = k0 + 32;
            #pragma unroll
            for (int i = 0; i < 4; ++i)
                av[i] = *(const float4*)(A + (size_t)(m0 + am + 32 * i) * 512 + kn + ak4);
            #pragma unroll
            for (int i = 0; i < 2; ++i) {
                bh4[i] = *(const uint4*)(BhT + (size_t)(n0 + bn + 64 * i) * 512 + kn + bk8);
                bl4[i] = *(const uint4*)(BlT + (size_t)(n0 + bn + 64 * i) * 512 + kn + bk8);
            }
        }
        bf16x8 afh[4], afl[4];
        #pragma unroll
        for (int ms = 0; ms < 4; ++ms) {
            int off = (wm + ms * 16 + l15) * 40 + quad * 8;
            afh[ms] = *(const bf16x8*)&Ah[off];
            afl[ms] = *(const bf16x8*)&Al[off];
        }
        #pragma unroll
        for (int ns = 0; ns < 4; ++ns) {
            int off = (wn + ns * 16 + l15) * 40 + quad * 8;
            bf16x8 bfh = *(const bf16x8*)&Bh[off];
            bf16x8 bfl = *(const bf16x8*)&Bl[off];
            #pragma unroll
            for (int ms = 0; ms < 4; ++ms) {
                acc[ms][ns] = MFMA16(afh[ms], bfl, acc[ms][ns]);
                acc[ms][ns] = MFMA16(afl[ms], bfh, acc[ms][ns]);
                acc[ms][ns] = MFMA16(afh[ms], bfh, acc[ms][ns]);
            }
        }
    }

    #pragma unroll
    for (int ns = 0; ns < 4; ++ns) {
        int col = n0 + wn + ns * 16 + l15;
        float bv = bias[col];
        #pragma unroll
        for (int ms = 0; ms < 4; ++ms) {
            #pragma unroll
            for (int r = 0; r < 4; ++r) {
                int row = m0 + wm + ms * 16 + quad * 4 + r;
                float v = acc[ms][ns][r] + bv;
                if (mode == 0) {
                    Cf[(size_t)row * 512 + col] = v;
                } else {
                    int h = col >> 6, d = col & 63;
                    int bb = row >> 11, rr = row & 2047;
                    size_t off = ((size_t)(bb * 8 + h) * 2048 + rr) * 64 + d;
                    ushort hv, lv; splitbf(v, hv, lv);
                    Ph[off] = hv; Pl[off] = lv;
                }
            }
        }
    }
}

// ---------------- Vf fp32 [8192][512] -> VhT/VlT bf16 [bh][d][key] (verified in R2) ----
__global__ __launch_bounds__(256) void vtrans_kernel(
    const float* __restrict__ Vf, ushort* __restrict__ VhT, ushort* __restrict__ VlT)
{
    __shared__ float T[64][65];
    const int bh = blockIdx.x, b = bh >> 3, h = bh & 7;
    const int key0 = blockIdx.y * 64;
    const int tid = threadIdx.x;
    #pragma unroll
    for (int i = 0; i < 4; ++i) {
        int u = tid + i * 256;
        int row = u >> 4, cc = (u & 15) * 4;
        float4 v = *(const float4*)(Vf + ((size_t)(b * 2048 + key0 + row)) * 512 + h * 64 + cc);
        T[row][cc + 0] = v.x; T[row][cc + 1] = v.y; T[row][cc + 2] = v.z; T[row][cc + 3] = v.w;
    }
    __syncthreads();
    #pragma unroll
    for (int i = 0; i < 2; ++i) {
        int u = tid + i * 256;
        int d = u >> 3, c8 = (u & 7) * 8;
        ushort hs[8], ls[8];
        #pragma unroll
        for (int j = 0; j < 8; ++j) splitbf(T[c8 + j][d], hs[j], ls[j]);
        uint4 wh, wl;
        wh.x = hs[0] | ((unsigned)hs[1] << 16); wh.y = hs[2] | ((unsigned)hs[3] << 16);
        wh.z = hs[4] | ((unsigned)hs[5] << 16); wh.w = hs[6] | ((unsigned)hs[7] << 16);
        wl.x = ls[0] | ((unsigned)ls[1] << 16); wl.y = ls[2] | ((unsigned)ls[3] << 16);
        wl.z = ls[4] | ((unsigned)ls[5] << 16); wl.w = ls[6] | ((unsigned)ls[7] << 16);
        size_t off = ((size_t)bh * 64 + d) * 2048 + key0 + c8;
        *(uint4*)(VhT + off) = wh;
        *(uint4*)(VlT + off) = wl;
    }
}

// ---------------- Flash attention, M=64/wave, async dbuf staging ----------------
// grid (32 bh, 8), block 256 = 4 waves; each wave: 64 q-rows, kv tiles of 64.
__global__ __launch_bounds__(256) void attn_mfma2_kernel(
    const ushort* __restrict__ Qh, const ushort* __restrict__ Ql,
    const ushort* __restrict__ Kh, const ushort* __restrict__ Kl,
    const ushort* __restrict__ VhT, const ushort* __restrict__ VlT,
    const int* __restrict__ mask, float* __restrict__ XS)
{
    // [buf][plane: Kh,Kl,Vh,Vl][row*64 + swizzled col] — XOR-swizzle, no pad (global_load_lds)
    __shared__ ushort KV[2][4][64 * 64];
    __shared__ uint Pp[4][64 * LDP];   // per-wave packed P (hi|lo<<16)

    const int tid = threadIdx.x;
    const int wave = tid >> 6, lane = tid & 63;
    const int l15 = lane & 15, quad = lane >> 4;
    const int bh = blockIdx.x, b = bh >> 3, h = bh & 7;
    const int q0 = blockIdx.y * 256;

    // Q fragments: A[m=l15][k=quad*8+j], rows wave*64 + qs*16 + l15
    bf16x8 qh[4][2], ql[4][2];
    #pragma unroll
    for (int qs = 0; qs < 4; ++qs) {
        size_t qb = ((size_t)bh * 2048 + q0 + wave * 64 + qs * 16 + l15) * 64 + quad * 8;
        qh[qs][0] = *(const bf16x8*)(Qh + qb);
        qh[qs][1] = *(const bf16x8*)(Qh + qb + 32);
        ql[qs][0] = *(const bf16x8*)(Ql + qb);
        ql[qs][1] = *(const bf16x8*)(Ql + qb + 32);
    }

    const f32x4 z = {0.f, 0.f, 0.f, 0.f};
    f32x4 oacc[4][4];
    #pragma unroll
    for (int i = 0; i < 4; ++i)
        #pragma unroll
        for (int j = 0; j < 4; ++j) oacc[i][j] = z;
    float lacc[4][4] = {};

    // staging source: wave w stages plane w. Lane: row_local = L>>3, slot = L&7,
    // source col-group = slot ^ row_local  (=> stored[row][g] = src[row][g ^ (row&7)])
    const int rloc = lane >> 3, gsrc = (lane & 7) ^ rloc;
    const ushort* gp0;
    size_t tstep, istep;
    if (wave == 0)      { gp0 = Kh  + ((size_t)bh * 2048 + rloc) * 64 + gsrc * 8; tstep = 64 * 64; istep = 8 * 64; }
    else if (wave == 1) { gp0 = Kl  + ((size_t)bh * 2048 + rloc) * 64 + gsrc * 8; tstep = 64 * 64; istep = 8 * 64; }
    else if (wave == 2) { gp0 = VhT + ((size_t)bh * 64 + rloc) * 2048 + gsrc * 8; tstep = 64;      istep = 8 * 2048; }
    else                { gp0 = VlT + ((size_t)bh * 64 + rloc) * 2048 + gsrc * 8; tstep = 64;      istep = 8 * 2048; }

    const int sw0 = (quad ^ (l15 & 7)) * 8;   // swizzled slot offset for group=quad
    const int mbase = b * 2048;

    // prologue: stage tile 0 into buf 0
    #pragma unroll
    for (int i = 0; i < 8; ++i)
        async16(gp0 + i * istep, &KV[0][wave][i * 512]);

    for (int t = 0; t < 32; ++t) {
        const int p = t & 1;
        if (t < 31) {
            #pragma unroll
            for (int i = 0; i < 8; ++i)
                async16(gp0 + (size_t)(t + 1) * tstep + i * istep, &KV[1 - p][wave][i * 512]);
        }
        __syncthreads();   // drains async loads of tile t; gates buffer reuse

        const int key0 = t * 64;
        int mv[4];
        #pragma unroll
        for (int nt = 0; nt < 4; ++nt) mv[nt] = mask[mbase + key0 + nt * 16 + l15];

        // ---- S = Q K^T, softmax, P pack ----
        #pragma unroll
        for (int nt = 0; nt < 4; ++nt) {
            const int rowoff = (nt * 16 + l15) * 64;
            bf16x8 kh0 = *(const bf16x8*)&KV[p][0][rowoff + sw0];
            bf16x8 kh1 = *(const bf16x8*)&KV[p][0][rowoff + (sw0 ^ 32)];
            bf16x8 kl0 = *(const bf16x8*)&KV[p][1][rowoff + sw0];
            bf16x8 kl1 = *(const bf16x8*)&KV[p][1][rowoff + (sw0 ^ 32)];
            float bias = mv[nt] ? 0.f : -1e30f;
            #pragma unroll
            for (int qs = 0; qs < 4; ++qs) {
                f32x4 a = z;
                a = MFMA16(ql[qs][0], kh0, a);
                a = MFMA16(ql[qs][1], kh1, a);
                a = MFMA16(qh[qs][0], kl0, a);
                a = MFMA16(qh[qs][1], kl1, a);
                a = MFMA16(qh[qs][0], kh0, a);
                a = MFMA16(qh[qs][1], kh1, a);
                #pragma unroll
                for (int r = 0; r < 4; ++r) {
                    float sv = a[r] * 0.125f + bias;
                    float pv = __expf(sv);
                    lacc[qs][r] += pv;
                    unsigned u = __float_as_uint(pv);
                    float hf = __uint_as_float(u & 0xffff0000u);
                    unsigned lo = __float_as_uint(pv - hf);
                    Pp[wave][(qs * 16 + quad * 4 + r) * LDP + nt * 16 + l15] =
                        (u >> 16) | (lo & 0xffff0000u);
                }
            }
        }

        // ---- O += P V ----
        #pragma unroll
        for (int ks = 0; ks < 2; ++ks) {
            const int svo = ks ? (sw0 ^ 32) : sw0;
            bf16x8 vh[4], vl[4];
            #pragma unroll
            for (int nt = 0; nt < 4; ++nt) {
                const int rowoff = (nt * 16 + l15) * 64;
                vh[nt] = *(const bf16x8*)&KV[p][2][rowoff + svo];
                vl[nt] = *(const bf16x8*)&KV[p][3][rowoff + svo];
            }
            #pragma unroll
            for (int qs = 0; qs < 4; ++qs) {
                const int idx = (qs * 16 + l15) * LDP + ks * 32 + quad * 8;
                uint4 u0 = *(const uint4*)&Pp[wave][idx];
                uint4 u1 = *(const uint4*)&Pp[wave][idx + 4];
                uint4 phu, plu;
                phu.x = __builtin_amdgcn_perm(u0.y, u0.x, 0x05040100u);
                phu.y = __builtin_amdgcn_perm(u0.w, u0.z, 0x05040100u);
                phu.z = __builtin_amdgcn_perm(u1.y, u1.x, 0x05040100u);
                phu.w = __builtin_amdgcn_perm(u1.w, u1.z, 0x05040100u);
                plu.x = __builtin_amdgcn_perm(u0.y, u0.x, 0x07060302u);
                plu.y = __builtin_amdgcn_perm(u0.w, u0.z, 0x07060302u);
                plu.z = __builtin_amdgcn_perm(u1.y, u1.x, 0x07060302u);
                plu.w = __builtin_amdgcn_perm(u1.w, u1.z, 0x07060302u);
                bf16x8 ph = *(const bf16x8*)&phu;
                bf16x8 pl = *(const bf16x8*)&plu;
                #pragma unroll
                for (int nt = 0; nt < 4; ++nt) {
                    oacc[qs][nt] = MFMA16(pl, vh[nt], oacc[qs][nt]);
                    oacc[qs][nt] = MFMA16(ph, vl[nt], oacc[qs][nt]);
                    oacc[qs][nt] = MFMA16(ph, vh[nt], oacc[qs][nt]);
                }
            }
        }
    }

    // epilogue: reduce l over the 16 key-lanes, normalize, write
    #pragma unroll
    for (int qs = 0; qs < 4; ++qs) {
        #pragma unroll
        for (int r = 0; r < 4; ++r) {
            float v = lacc[qs][r];
            v += __shfl_xor(v, 1); v += __shfl_xor(v, 2);
            v += __shfl_xor(v, 4); v += __shfl_xor(v, 8);
            float inv = (v > 0.f) ? 1.f / v : 0.f;
            int row = q0 + wave * 64 + qs * 16 + quad * 4 + r;
            float* rowp = XS + ((size_t)(b * 2048 + row)) * 512 + h * 64 + l15;
            #pragma unroll
            for (int nt = 0; nt < 4; ++nt)
                rowp[nt * 16] = oacc[qs][nt][r] * inv;
        }
    }
}

extern "C" void kernel_launch(void* const* d_in, const int* in_sizes, int n_in,
                              void* d_out, int out_size, void* d_ws, size_t ws_size,
                              hipStream_t stream) {
    const float* query = (const float*)d_in[0];
    const float* key   = (const float*)d_in[1];
    const float* value = (const float*)d_in[2];
    const int*   mask  = (const int*)d_in[3];
    const float* Wq = (const float*)d_in[4];
    const float* bq = (const float*)d_in[5];
    const float* Wk = (const float*)d_in[6];
    const float* bk = (const float*)d_in[7];
    const float* Wv = (const float*)d_in[8];
    const float* bv = (const float*)d_in[9];
    const float* Wo = (const float*)d_in[10];
    const float* bo = (const float*)d_in[11];

    char* w = (char*)d_ws;
    const size_t MB = (size_t)1 << 20;
    ushort* Qh  = (ushort*)(w + 0 * MB);
    ushort* Ql  = (ushort*)(w + 8 * MB);
    ushort* Kh  = (ushort*)(w + 16 * MB);
    ushort* Kl  = (ushort*)(w + 24 * MB);
    ushort* VhT = (ushort*)(w + 32 * MB);
    ushort* VlT = (ushort*)(w + 40 * MB);
    float*  Vf  = (float*)(w + 48 * MB);    // 16 MB; reused as XS after vtrans
    float*  XS  = Vf;
    // QKV weight pairs live in d_out (free until final GEMM); Wo pair reuses dead Qh region
    ushort* WTh = (ushort*)d_out;
    ushort* WTl = (ushort*)d_out + 512 * 512;
    ushort* WoTh = (ushort*)(w + 0 * MB);
    ushort* WoTl = (ushort*)(w + 0 * MB) + 512 * 512 * sizeof(ushort);

    dim3 gw(8, 8), gg(64, 4);

    wsplit_kernel<<<gw, 256, 0, stream>>>(Wq, WTh, WTl);
    gemm_split_kernel<<<gg, 256, 0, stream>>>(query, WTh, WTl, bq, 1, nullptr, Qh, Ql);
    wsplit_kernel<<<gw, 256, 0, stream>>>(Wk, WTh, WTl);
    gemm_split_kernel<<<gg, 256, 0, stream>>>(key, WTh, WTl, bk, 1, nullptr, Kh, Kl);
    wsplit_kernel<<<gw, 256, 0, stream>>>(Wv, WTh, WTl);
    gemm_split_kernel<<<gg, 256, 0, stream>>>(value, WTh, WTl, bv, 0, Vf, nullptr, nullptr);
    vtrans_kernel<<<dim3(32, 32), 256, 0, stream>>>(Vf, VhT, VlT);
    attn_mfma2_kernel<<<dim3(32, 8), 256, 0, stream>>>(Qh, Ql, Kh, Kl, VhT, VlT, mask, XS);
    wsplit_kernel<<<gw, 256, 0, stream>>>(Wo, WoTh, WoTl);
    gemm_split_kernel<<<gg, 256, 0, stream>>>(XS, WoTh, WoTl, bo, 0, (float*)d_out, nullptr, nullptr);
}

// Round 4
// 335.611 us; speedup vs baseline: 3.0907x; 1.1622x over previous
//
#include <hip/hip_runtime.h>
#include <math.h>

#define Bq 4
#define Lq 2048
#define NH 8
#define LDP2 40   // Pp row stride (ushorts): 32 keys + 8 pad

typedef __attribute__((ext_vector_type(8))) __bf16 bf16x8;
typedef __attribute__((ext_vector_type(4))) float f32x4;
#define MFMA16(a,b,c) __builtin_amdgcn_mfma_f32_16x16x32_bf16(a,b,c,0,0,0)

__device__ __forceinline__ void async16(const void* g, void* l) {
    __builtin_amdgcn_global_load_lds(
        (const __attribute__((address_space(1))) unsigned int*)g,
        (__attribute__((address_space(3))) unsigned int*)l, 16, 0, 0);
}

// truncation split: x = hi + lo (+ ~2^-16 rel residual)
__device__ __forceinline__ void splitbf(float x, ushort& h, ushort& l) {
    unsigned u = __float_as_uint(x);
    h = (ushort)(u >> 16);
    float hf = __uint_as_float(u & 0xffff0000u);
    l = (ushort)(__float_as_uint(x - hf) >> 16);
}
// round-to-nearest-even bf16
__device__ __forceinline__ ushort rnebf(float x) {
    unsigned u = __float_as_uint(x);
    return (ushort)((u + 0x7fffu + ((u >> 16) & 1u)) >> 16);
}

// ---- W [512k][512n] fp32 -> WT [z*512 + n][k] bf16 hi/lo planes (z selects source) ----
__global__ __launch_bounds__(256) void wsplit3_kernel(
    const float* __restrict__ W0, const float* __restrict__ W1, const float* __restrict__ W2,
    ushort* __restrict__ WTh, ushort* __restrict__ WTl)
{
    __shared__ float T[64][65];
    const int z = blockIdx.z;
    const float* W = (z == 0) ? W0 : (z == 1) ? W1 : W2;
    const int k0 = blockIdx.x * 64, n0 = blockIdx.y * 64;
    const int tid = threadIdx.x;
    #pragma unroll
    for (int i = 0; i < 4; ++i) {
        int u = tid + i * 256;
        int row = u >> 4, c4 = (u & 15) * 4;
        float4 v = *(const float4*)(W + (size_t)(k0 + row) * 512 + n0 + c4);
        T[row][c4 + 0] = v.x; T[row][c4 + 1] = v.y; T[row][c4 + 2] = v.z; T[row][c4 + 3] = v.w;
    }
    __syncthreads();
    #pragma unroll
    for (int i = 0; i < 2; ++i) {
        int u = tid + i * 256;
        int d = u >> 3, c8 = (u & 7) * 8;
        ushort hs[8], ls[8];
        #pragma unroll
        for (int j = 0; j < 8; ++j) splitbf(T[c8 + j][d], hs[j], ls[j]);
        uint4 wh, wl;
        wh.x = hs[0] | ((unsigned)hs[1] << 16); wh.y = hs[2] | ((unsigned)hs[3] << 16);
        wh.z = hs[4] | ((unsigned)hs[5] << 16); wh.w = hs[6] | ((unsigned)hs[7] << 16);
        wl.x = ls[0] | ((unsigned)ls[1] << 16); wl.y = ls[2] | ((unsigned)ls[3] << 16);
        wl.z = ls[4] | ((unsigned)ls[5] << 16); wl.w = ls[6] | ((unsigned)ls[7] << 16);
        size_t off = (size_t)(z * 512 + n0 + d) * 512 + k0 + c8;
        *(uint4*)(WTh + off) = wh;
        *(uint4*)(WTl + off) = wl;
    }
}

// ---- split-bf16 MFMA GEMM over virtual [8192][nTot] output; per-range A/bias/epilogue ----
// final==0: mi=0 -> Q split planes, mi=1 -> Kh (RNE) plane, mi=2 -> fp32 Vf
// final==1: fp32 to Cf
__global__ __launch_bounds__(256) void gemm_qkv_kernel(
    const float* __restrict__ A0, const float* __restrict__ A1, const float* __restrict__ A2,
    const ushort* __restrict__ BhT, const ushort* __restrict__ BlT,
    const float* __restrict__ b0, const float* __restrict__ b1, const float* __restrict__ b2,
    int final_, float* __restrict__ Cf,
    ushort* __restrict__ Qh, ushort* __restrict__ Ql,
    ushort* __restrict__ Khp, float* __restrict__ Vf)
{
    __shared__ ushort Ah[128 * 40], Al[128 * 40], Bh[128 * 40], Bl[128 * 40];
    const int tid = threadIdx.x;
    const int wave = tid >> 6, lane = tid & 63;
    const int l15 = lane & 15, quad = lane >> 4;
    const int m0 = blockIdx.x * 128, n0 = blockIdx.y * 128;
    const int mi = n0 >> 9;
    const float* A = final_ ? A0 : (mi == 0 ? A0 : (mi == 1 ? A1 : A2));
    const float* bias = final_ ? b0 : (mi == 0 ? b0 : (mi == 1 ? b1 : b2));
    const int wm = (wave >> 1) * 64, wn = (wave & 1) * 64;

    const int am = tid >> 3, ak4 = (tid & 7) * 4;
    const int bn = tid >> 2, bk8 = (tid & 3) * 8;

    f32x4 acc[4][4];
    #pragma unroll
    for (int i = 0; i < 4; ++i)
        #pragma unroll
        for (int j = 0; j < 4; ++j) acc[i][j] = (f32x4){0.f, 0.f, 0.f, 0.f};

    float4 av[4]; uint4 bh4[2], bl4[2];
    #pragma unroll
    for (int i = 0; i < 4; ++i)
        av[i] = *(const float4*)(A + (size_t)(m0 + am + 32 * i) * 512 + ak4);
    #pragma unroll
    for (int i = 0; i < 2; ++i) {
        bh4[i] = *(const uint4*)(BhT + (size_t)(n0 + bn + 64 * i) * 512 + bk8);
        bl4[i] = *(const uint4*)(BlT + (size_t)(n0 + bn + 64 * i) * 512 + bk8);
    }

    for (int k0 = 0; k0 < 512; k0 += 32) {
        __syncthreads();
        #pragma unroll
        for (int i = 0; i < 4; ++i) {
            ushort4 h4, l4;
            splitbf(av[i].x, h4.x, l4.x); splitbf(av[i].y, h4.y, l4.y);
            splitbf(av[i].z, h4.z, l4.z); splitbf(av[i].w, h4.w, l4.w);
            *(ushort4*)&Ah[(am + 32 * i) * 40 + ak4] = h4;
            *(ushort4*)&Al[(am + 32 * i) * 40 + ak4] = l4;
        }
        #pragma unroll
        for (int i = 0; i < 2; ++i) {
            *(uint4*)&Bh[(bn + 64 * i) * 40 + bk8] = bh4[i];
            *(uint4*)&Bl[(bn + 64 * i) * 40 + bk8] = bl4[i];
        }
        __syncthreads();
        if (k0 < 480) {
            int kn = k0 + 32;
            #pragma unroll
            for (int i = 0; i < 4; ++i)
                av[i] = *(const float4*)(A + (size_t)(m0 + am + 32 * i) * 512 + kn + ak4);
            #pragma unroll
            for (int i = 0; i < 2; ++i) {
                bh4[i] = *(const uint4*)(BhT + (size_t)(n0 + bn + 64 * i) * 512 + kn + bk8);
                bl4[i] = *(const uint4*)(BlT + (size_t)(n0 + bn + 64 * i) * 512 + kn + bk8);
            }
        }
        bf16x8 afh[4], afl[4];
        #pragma unroll
        for (int ms = 0; ms < 4; ++ms) {
            int off = (wm + ms * 16 + l15) * 40 + quad * 8;
            afh[ms] = *(const bf16x8*)&Ah[off];
            afl[ms] = *(const bf16x8*)&Al[off];
        }
        #pragma unroll
        for (int ns = 0; ns < 4; ++ns) {
            int off = (wn + ns * 16 + l15) * 40 + quad * 8;
            bf16x8 bfh = *(const bf16x8*)&Bh[off];
            bf16x8 bfl = *(const bf16x8*)&Bl[off];
            #pragma unroll
            for (int ms = 0; ms < 4; ++ms) {
                acc[ms][ns] = MFMA16(afh[ms], bfl, acc[ms][ns]);
                acc[ms][ns] = MFMA16(afl[ms], bfh, acc[ms][ns]);
                acc[ms][ns] = MFMA16(afh[ms], bfh, acc[ms][ns]);
            }
        }
    }

    #pragma unroll
    for (int ns = 0; ns < 4; ++ns) {
        int colg = n0 + wn + ns * 16 + l15;
        int col = colg & 511;
        float bv = bias[col];
        #pragma unroll
        for (int ms = 0; ms < 4; ++ms) {
            #pragma unroll
            for (int r = 0; r < 4; ++r) {
                int row = m0 + wm + ms * 16 + quad * 4 + r;
                float v = acc[ms][ns][r] + bv;
                if (final_) {
                    Cf[(size_t)row * 512 + col] = v;
                } else {
                    int h = col >> 6, d = col & 63;
                    int bb = row >> 11, rr = row & 2047;
                    size_t off = ((size_t)(bb * 8 + h) * 2048 + rr) * 64 + d;
                    if (mi == 0) { ushort hv, lv; splitbf(v, hv, lv); Qh[off] = hv; Ql[off] = lv; }
                    else if (mi == 1) { Khp[off] = rnebf(v); }
                    else { Vf[(size_t)row * 512 + col] = v; }
                }
            }
        }
    }
}

// ---- Vf fp32 [8192][512] -> VhT/VlT bf16 [bh][d][key] ----
__global__ __launch_bounds__(256) void vtrans_kernel(
    const float* __restrict__ Vf, ushort* __restrict__ VhT, ushort* __restrict__ VlT)
{
    __shared__ float T[64][65];
    const int bh = blockIdx.x, b = bh >> 3, h = bh & 7;
    const int key0 = blockIdx.y * 64;
    const int tid = threadIdx.x;
    #pragma unroll
    for (int i = 0; i < 4; ++i) {
        int u = tid + i * 256;
        int row = u >> 4, cc = (u & 15) * 4;
        float4 v = *(const float4*)(Vf + ((size_t)(b * 2048 + key0 + row)) * 512 + h * 64 + cc);
        T[row][cc + 0] = v.x; T[row][cc + 1] = v.y; T[row][cc + 2] = v.z; T[row][cc + 3] = v.w;
    }
    __syncthreads();
    #pragma unroll
    for (int i = 0; i < 2; ++i) {
        int u = tid + i * 256;
        int d = u >> 3, c8 = (u & 7) * 8;
        ushort hs[8], ls[8];
        #pragma unroll
        for (int j = 0; j < 8; ++j) splitbf(T[c8 + j][d], hs[j], ls[j]);
        uint4 wh, wl;
        wh.x = hs[0] | ((unsigned)hs[1] << 16); wh.y = hs[2] | ((unsigned)hs[3] << 16);
        wh.z = hs[4] | ((unsigned)hs[5] << 16); wh.w = hs[6] | ((unsigned)hs[7] << 16);
        wl.x = ls[0] | ((unsigned)ls[1] << 16); wl.y = ls[2] | ((unsigned)ls[3] << 16);
        wl.z = ls[4] | ((unsigned)ls[5] << 16); wl.w = ls[6] | ((unsigned)ls[7] << 16);
        size_t off = ((size_t)bh * 64 + d) * 2048 + key0 + c8;
        *(uint4*)(VhT + off) = wh;
        *(uint4*)(VlT + off) = wl;
    }
}

// ---- Flash attention, S^T dataflow, in-block split-K, async dbuf, 512 threads ----
// grid (32 bh, 8). Waves 0-3: keys 0-1023; waves 4-7: keys 1024-2047. 256 q-rows/block.
union SmemU {
    struct { ushort KVs[2][6][4096]; ushort Pp[8][64 * LDP2]; } p1;  // 96K + 40K
    struct { float Obuf[4][64 * 68]; float Lbuf[4][64]; } p2;        // 68K + 1K
};

__global__ __launch_bounds__(512, 2) void attn3_kernel(
    const ushort* __restrict__ Qh, const ushort* __restrict__ Ql,
    const ushort* __restrict__ Kh, const ushort* __restrict__ VhT,
    const ushort* __restrict__ VlT, const int* __restrict__ mask,
    float* __restrict__ XS)
{
    __shared__ SmemU smem;
    const int tid = threadIdx.x;
    const int wave = tid >> 6, lane = tid & 63;
    const int l15 = lane & 15, quad = lane >> 4;
    const int w4 = wave & 3, half = wave >> 2;
    const int bh = blockIdx.x, b = bh >> 3, h = bh & 7;
    const int q0 = blockIdx.y * 256;

    // Q fragments (B-operand: B[k=d=quad*8+j][n=qrow=l15]) — read from row-major Q planes
    bf16x8 qh[4][2], ql[4][2];
    #pragma unroll
    for (int qs = 0; qs < 4; ++qs) {
        size_t qb = ((size_t)bh * 2048 + q0 + w4 * 64 + qs * 16 + l15) * 64 + quad * 8;
        qh[qs][0] = *(const bf16x8*)(Qh + qb);
        qh[qs][1] = *(const bf16x8*)(Qh + qb + 32);
        ql[qs][0] = *(const bf16x8*)(Ql + qb);
        ql[qs][1] = *(const bf16x8*)(Ql + qb + 32);
    }

    const f32x4 z = {0.f, 0.f, 0.f, 0.f};
    f32x4 oacc[4][4];   // [qs][dsub], C-layout: col=qrow=l15, row=d=quad*4+r
    #pragma unroll
    for (int i = 0; i < 4; ++i)
        #pragma unroll
        for (int j = 0; j < 4; ++j) oacc[i][j] = z;
    float lacc[4] = {0.f, 0.f, 0.f, 0.f};

    // staging descriptors: 48 chunks (2 halves x 3 planes x 8), wave w -> chunks w*6..w*6+5
    const int rloc = lane >> 3, gs = (lane & 7) ^ rloc;  // XOR-swizzled source col-group
    const ushort* sb[6]; size_t sstep[6]; int dofs[6];
    #pragma unroll
    for (int i = 0; i < 6; ++i) {
        int cc = wave * 6 + i;
        int hc = cc / 24, r24 = cc % 24, pc = r24 >> 3, ic = r24 & 7;
        if (pc == 0) {
            sb[i] = Kh + ((size_t)(bh * 2048 + hc * 1024 + ic * 8 + rloc)) * 64 + gs * 8;
            sstep[i] = (size_t)64 * 64;
        } else {
            const ushort* vp = (pc == 1) ? VhT : VlT;
            sb[i] = vp + ((size_t)(bh * 64 + ic * 8 + rloc)) * 2048 + hc * 1024 + gs * 8;
            sstep[i] = 64;
        }
        dofs[i] = (hc * 3 + pc) * 4096 + ic * 512;
    }

    const int sw0 = (quad ^ (l15 & 7)) * 8;   // swizzled read offset, chunk0
    const int mrow0 = b * 2048 + half * 1024;

    // prologue: stage tile 0 into buf 0
    #pragma unroll
    for (int i = 0; i < 6; ++i)
        async16(sb[i], &smem.p1.KVs[0][0][0] + dofs[i]);

    for (int t = 0; t < 16; ++t) {
        __syncthreads();   // drains DMA(t); all waves done reading buf (t+1)&1
        if (t < 15) {
            #pragma unroll
            for (int i = 0; i < 6; ++i)
                async16(sb[i] + (size_t)(t + 1) * sstep[i], &smem.p1.KVs[(t + 1) & 1][0][0] + dofs[i]);
        }
        const int p = t & 1;
        const ushort* K0 = smem.p1.KVs[p][half * 3 + 0];
        const ushort* V0 = smem.p1.KVs[p][half * 3 + 1];
        const ushort* V1 = smem.p1.KVs[p][half * 3 + 2];
        ushort* Pw = smem.p1.Pp[wave];

        #pragma unroll
        for (int ks = 0; ks < 2; ++ks) {
            // ---- S^T = K · Q^T for 32 keys (2 sub-tiles of 16) ----
            #pragma unroll
            for (int kt2 = 0; kt2 < 2; ++kt2) {
                const int kt = ks * 2 + kt2;
                const int kb = (kt * 16 + l15) * 64;
                bf16x8 ka0 = *(const bf16x8*)&K0[kb + sw0];
                bf16x8 ka1 = *(const bf16x8*)&K0[kb + (sw0 ^ 32)];
                int4 mv = *(const int4*)(mask + mrow0 + t * 64 + kt * 16 + quad * 4);
                float bias[4];
                bias[0] = mv.x ? 0.f : -1e30f; bias[1] = mv.y ? 0.f : -1e30f;
                bias[2] = mv.z ? 0.f : -1e30f; bias[3] = mv.w ? 0.f : -1e30f;
                #pragma unroll
                for (int qs = 0; qs < 4; ++qs) {
                    f32x4 a = z;
                    a = MFMA16(ka0, ql[qs][0], a);
                    a = MFMA16(ka1, ql[qs][1], a);
                    a = MFMA16(ka0, qh[qs][0], a);
                    a = MFMA16(ka1, qh[qs][1], a);
                    ushort4 hv;
                    #pragma unroll
                    for (int r = 0; r < 4; ++r) {
                        float pv = __expf(a[r] * 0.125f + bias[r]);
                        unsigned u = __float_as_uint(pv);
                        unsigned hu = (u + 0x7fffu + ((u >> 16) & 1u)) & 0xffff0000u;
                        lacc[qs] += __uint_as_float(hu);
                        ((ushort*)&hv)[r] = (ushort)(hu >> 16);
                    }
                    *(ushort4*)&Pw[(qs * 16 + l15) * LDP2 + kt2 * 16 + quad * 4] = hv;
                }
            }
            // ---- O^T += V^T · P^T for these 32 keys ----
            const int svo = sw0 ^ (ks * 32);
            bf16x8 pf[4];
            #pragma unroll
            for (int qs = 0; qs < 4; ++qs)
                pf[qs] = *(const bf16x8*)&Pw[(qs * 16 + l15) * LDP2 + quad * 8];
            #pragma unroll
            for (int dsub = 0; dsub < 4; ++dsub) {
                const int vb = (dsub * 16 + l15) * 64;
                bf16x8 vh = *(const bf16x8*)&V0[vb + svo];
                bf16x8 vl = *(const bf16x8*)&V1[vb + svo];
                #pragma unroll
                for (int qs = 0; qs < 4; ++qs) {
                    oacc[qs][dsub] = MFMA16(vl, pf[qs], oacc[qs][dsub]);
                    oacc[qs][dsub] = MFMA16(vh, pf[qs], oacc[qs][dsub]);
                }
            }
        }
    }

    // l: reduce over the 4 quads (lanes sharing l15)
    float lv[4];
    #pragma unroll
    for (int qs = 0; qs < 4; ++qs) {
        float v = lacc[qs];
        v += __shfl_xor(v, 16);
        v += __shfl_xor(v, 32);
        lv[qs] = v;
    }

    __syncthreads();   // all tile reads done; safe to alias phase-2 buffers
    if (half == 1) {
        #pragma unroll
        for (int qs = 0; qs < 4; ++qs) {
            #pragma unroll
            for (int dsub = 0; dsub < 4; ++dsub) {
                float4 o4 = {oacc[qs][dsub][0], oacc[qs][dsub][1], oacc[qs][dsub][2], oacc[qs][dsub][3]};
                *(float4*)&smem.p2.Obuf[w4][(qs * 16 + l15) * 68 + dsub * 16 + quad * 4] = o4;
            }
            if (quad == 0) smem.p2.Lbuf[w4][qs * 16 + l15] = lv[qs];
        }
    }
    __syncthreads();
    if (half == 0) {
        #pragma unroll
        for (int qs = 0; qs < 4; ++qs) {
            float ltot = lv[qs] + smem.p2.Lbuf[w4][qs * 16 + l15];
            float inv = (ltot > 0.f) ? 1.f / ltot : 0.f;
            int row = q0 + w4 * 64 + qs * 16 + l15;
            float* rowp = XS + ((size_t)(b * 2048 + row)) * 512 + h * 64;
            #pragma unroll
            for (int dsub = 0; dsub < 4; ++dsub) {
                float4 p4 = *(const float4*)&smem.p2.Obuf[w4][(qs * 16 + l15) * 68 + dsub * 16 + quad * 4];
                float4 o4;
                o4.x = (oacc[qs][dsub][0] + p4.x) * inv;
                o4.y = (oacc[qs][dsub][1] + p4.y) * inv;
                o4.z = (oacc[qs][dsub][2] + p4.z) * inv;
                o4.w = (oacc[qs][dsub][3] + p4.w) * inv;
                *(float4*)(rowp + dsub * 16 + quad * 4) = o4;
            }
        }
    }
}

extern "C" void kernel_launch(void* const* d_in, const int* in_sizes, int n_in,
                              void* d_out, int out_size, void* d_ws, size_t ws_size,
                              hipStream_t stream) {
    const float* query = (const float*)d_in[0];
    const float* key   = (const float*)d_in[1];
    const float* value = (const float*)d_in[2];
    const int*   mask  = (const int*)d_in[3];
    const float* Wq = (const float*)d_in[4];
    const float* bq = (const float*)d_in[5];
    const float* Wk = (const float*)d_in[6];
    const float* bk = (const float*)d_in[7];
    const float* Wv = (const float*)d_in[8];
    const float* bv = (const float*)d_in[9];
    const float* Wo = (const float*)d_in[10];
    const float* bo = (const float*)d_in[11];

    char* w = (char*)d_ws;
    const size_t MB = (size_t)1 << 20;
    ushort* Qh  = (ushort*)(w + 0 * MB);
    ushort* Ql  = (ushort*)(w + 8 * MB);
    ushort* Khp = (ushort*)(w + 16 * MB);
    ushort* VhT = (ushort*)(w + 24 * MB);
    ushort* VlT = (ushort*)(w + 32 * MB);
    float*  Vf  = (float*)(w + 40 * MB);   // dead after vtrans
    float*  XS  = (float*)(w + 40 * MB);   // overlays Vf (attn reads VhT/VlT only)
    ushort* WTh = (ushort*)(w + 56 * MB);          // [1536][512]
    ushort* WTl = WTh + (size_t)1536 * 512;

    // Vf and XS overlap — but vtrans finishes before attn writes XS. OK.
    // Except Vf must survive until vtrans: place XS separately to be safe? No:
    // attn (writer of XS) launches strictly after vtrans (reader of Vf). Safe.

    wsplit3_kernel<<<dim3(8, 8, 3), 256, 0, stream>>>(Wq, Wk, Wv, WTh, WTl);
    gemm_qkv_kernel<<<dim3(64, 12), 256, 0, stream>>>(
        query, key, value, WTh, WTl, bq, bk, bv, 0, nullptr, Qh, Ql, Khp, Vf);
    vtrans_kernel<<<dim3(32, 32), 256, 0, stream>>>(Vf, VhT, VlT);
    attn3_kernel<<<dim3(32, 8), 512, 0, stream>>>(Qh, Ql, Khp, VhT, VlT, mask, XS);
    wsplit3_kernel<<<dim3(8, 8, 1), 256, 0, stream>>>(Wo, Wo, Wo, WTh, WTl);
    gemm_qkv_kernel<<<dim3(64, 4), 256, 0, stream>>>(
        XS, XS, XS, WTh, WTl, bo, bo, bo, 1, (float*)d_out, nullptr, nullptr, nullptr, nullptr);
}

// Round 5
// 279.895 us; speedup vs baseline: 3.7059x; 1.1991x over previous
//
#include <hip/hip_runtime.h>
#include <math.h>

#define Bq 4
#define Lq 2048
#define NH 8
#define LDP2 40   // attn Pp row stride (ushorts)

typedef __attribute__((ext_vector_type(8))) __bf16 bf16x8;
typedef __attribute__((ext_vector_type(4))) float f32x4;
#define MFMA16(a,b,c) __builtin_amdgcn_mfma_f32_16x16x32_bf16(a,b,c,0,0,0)

__device__ __forceinline__ void async16(const void* g, void* l) {
    __builtin_amdgcn_global_load_lds(
        (const __attribute__((address_space(1))) unsigned int*)g,
        (__attribute__((address_space(3))) unsigned int*)l, 16, 0, 0);
}

// truncation split: x = hi + lo (+ ~2^-16 rel residual)
__device__ __forceinline__ void splitbf(float x, ushort& h, ushort& l) {
    unsigned u = __float_as_uint(x);
    h = (ushort)(u >> 16);
    float hf = __uint_as_float(u & 0xffff0000u);
    l = (ushort)(__float_as_uint(x - hf) >> 16);
}
// round-to-nearest-even bf16
__device__ __forceinline__ ushort rnebf(float x) {
    unsigned u = __float_as_uint(x);
    return (ushort)((u + 0x7fffu + ((u >> 16) & 1u)) >> 16);
}

// ---- W [512k][512n] fp32 -> WT [z*512 + n][k] bf16 hi/lo planes ----
__global__ __launch_bounds__(256) void wsplit3_kernel(
    const float* __restrict__ W0, const float* __restrict__ W1, const float* __restrict__ W2,
    ushort* __restrict__ WTh, ushort* __restrict__ WTl)
{
    __shared__ float T[64][65];
    const int z = blockIdx.z;
    const float* W = (z == 0) ? W0 : (z == 1) ? W1 : W2;
    const int k0 = blockIdx.x * 64, n0 = blockIdx.y * 64;
    const int tid = threadIdx.x;
    #pragma unroll
    for (int i = 0; i < 4; ++i) {
        int u = tid + i * 256;
        int row = u >> 4, c4 = (u & 15) * 4;
        float4 v = *(const float4*)(W + (size_t)(k0 + row) * 512 + n0 + c4);
        T[row][c4 + 0] = v.x; T[row][c4 + 1] = v.y; T[row][c4 + 2] = v.z; T[row][c4 + 3] = v.w;
    }
    __syncthreads();
    #pragma unroll
    for (int i = 0; i < 2; ++i) {
        int u = tid + i * 256;
        int d = u >> 3, c8 = (u & 7) * 8;
        ushort hs[8], ls[8];
        #pragma unroll
        for (int j = 0; j < 8; ++j) splitbf(T[c8 + j][d], hs[j], ls[j]);
        uint4 wh, wl;
        wh.x = hs[0] | ((unsigned)hs[1] << 16); wh.y = hs[2] | ((unsigned)hs[3] << 16);
        wh.z = hs[4] | ((unsigned)hs[5] << 16); wh.w = hs[6] | ((unsigned)hs[7] << 16);
        wl.x = ls[0] | ((unsigned)ls[1] << 16); wl.y = ls[2] | ((unsigned)ls[3] << 16);
        wl.z = ls[4] | ((unsigned)ls[5] << 16); wl.w = ls[6] | ((unsigned)ls[7] << 16);
        size_t off = (size_t)(z * 512 + n0 + d) * 512 + k0 + c8;
        *(uint4*)(WTh + off) = wh;
        *(uint4*)(WTl + off) = wl;
    }
}

// ---- GEMM2: 128x64 tile, BK=32, 4 waves (64x32 each), dbuf async-B staging ----
// final_=0: mi = y>>3 selects 0->Q split planes, 1->K hi plane, 2->V^T split planes
// final_=1: fp32 out to Cf
union GS {
    struct {
        ushort Ah[2][128 * 40];
        ushort Al[2][128 * 40];
        ushort Bh[2][2048];
        ushort Bl[2][2048];
    } s;
    ushort E[57344 / 2];
};

__global__ __launch_bounds__(256) void gemm2_kernel(
    const float* __restrict__ A0, const float* __restrict__ A1, const float* __restrict__ A2,
    const ushort* __restrict__ BhT, const ushort* __restrict__ BlT,
    const float* __restrict__ b0, const float* __restrict__ b1, const float* __restrict__ b2,
    int final_, float* __restrict__ Cf,
    ushort* __restrict__ Qh, ushort* __restrict__ Ql, ushort* __restrict__ Khp,
    ushort* __restrict__ VhT, ushort* __restrict__ VlT)
{
    __shared__ __align__(16) GS gs;
    const int tid = threadIdx.x;
    const int wave = tid >> 6, lane = tid & 63;
    const int l15 = lane & 15, quad = lane >> 4;
    const int m0 = blockIdx.x * 128;
    const int yy = blockIdx.y;
    const int mi = yy >> 3, n0 = (yy & 7) * 64;
    const int nglob = mi * 512 + n0;
    const float* A = (mi == 0) ? A0 : (mi == 1) ? A1 : A2;
    const float* bias = (mi == 0) ? b0 : (mi == 1) ? b1 : b2;
    const int wm = (wave & 1) * 64, wn = (wave >> 1) * 32;

    // A staging (register path, needs splitbf): rows am+32i, chunk ak4
    const int am = tid >> 3, ak4 = (tid & 7) * 4;
    // B staging (async): wave stages rows wave*16..+15 of both planes, XOR-swizzled
    const int brow = lane >> 2, bsrc = (lane & 3) ^ (brow & 3);
    const ushort* bhp = BhT + (size_t)(nglob + wave * 16 + brow) * 512 + bsrc * 8;
    const ushort* blp = BlT + (size_t)(nglob + wave * 16 + brow) * 512 + bsrc * 8;
    const int bdst = wave * 512 + lane * 8;   // ushort idx; byte = uniform + lane*16

    f32x4 acc[4][2];
    #pragma unroll
    for (int i = 0; i < 4; ++i)
        #pragma unroll
        for (int j = 0; j < 2; ++j) acc[i][j] = (f32x4){0.f, 0.f, 0.f, 0.f};

    float4 av[4];
    #pragma unroll
    for (int i = 0; i < 4; ++i)
        av[i] = *(const float4*)(A + (size_t)(m0 + am + 32 * i) * 512 + ak4);
    async16(bhp, &gs.s.Bh[0][bdst]);
    async16(blp, &gs.s.Bl[0][bdst]);
    #pragma unroll
    for (int i = 0; i < 4; ++i) {
        ushort4 h4, l4;
        splitbf(av[i].x, h4.x, l4.x); splitbf(av[i].y, h4.y, l4.y);
        splitbf(av[i].z, h4.z, l4.z); splitbf(av[i].w, h4.w, l4.w);
        *(ushort4*)&gs.s.Ah[0][(am + 32 * i) * 40 + ak4] = h4;
        *(ushort4*)&gs.s.Al[0][(am + 32 * i) * 40 + ak4] = l4;
    }

    for (int t = 0; t < 16; ++t) {
        const int p = t & 1;
        __syncthreads();   // drains async B(t) + A writes(t); all reads of buf 1-p done
        if (t < 15) {
            const int kn = (t + 1) * 32;
            async16(bhp + kn, &gs.s.Bh[1 - p][bdst]);
            async16(blp + kn, &gs.s.Bl[1 - p][bdst]);
            #pragma unroll
            for (int i = 0; i < 4; ++i)
                av[i] = *(const float4*)(A + (size_t)(m0 + am + 32 * i) * 512 + kn + ak4);
        }
        bf16x8 afh[4], afl[4];
        #pragma unroll
        for (int ms = 0; ms < 4; ++ms) {
            int off = (wm + ms * 16 + l15) * 40 + quad * 8;
            afh[ms] = *(const bf16x8*)&gs.s.Ah[p][off];
            afl[ms] = *(const bf16x8*)&gs.s.Al[p][off];
        }
        #pragma unroll
        for (int ns = 0; ns < 2; ++ns) {
            int off = (wn + ns * 16 + l15) * 32 + (quad ^ (l15 & 3)) * 8;
            bf16x8 bfh = *(const bf16x8*)&gs.s.Bh[p][off];
            bf16x8 bfl = *(const bf16x8*)&gs.s.Bl[p][off];
            #pragma unroll
            for (int ms = 0; ms < 4; ++ms) {
                acc[ms][ns] = MFMA16(afh[ms], bfl, acc[ms][ns]);
                acc[ms][ns] = MFMA16(afl[ms], bfh, acc[ms][ns]);
                acc[ms][ns] = MFMA16(afh[ms], bfh, acc[ms][ns]);
            }
        }
        if (t < 15) {
            #pragma unroll
            for (int i = 0; i < 4; ++i) {
                ushort4 h4, l4;
                splitbf(av[i].x, h4.x, l4.x); splitbf(av[i].y, h4.y, l4.y);
                splitbf(av[i].z, h4.z, l4.z); splitbf(av[i].w, h4.w, l4.w);
                *(ushort4*)&gs.s.Ah[1 - p][(am + 32 * i) * 40 + ak4] = h4;
                *(ushort4*)&gs.s.Al[1 - p][(am + 32 * i) * 40 + ak4] = l4;
            }
        }
    }

    // bias
    #pragma unroll
    for (int ns = 0; ns < 2; ++ns) {
        float bv = bias[n0 + wn + ns * 16 + l15];
        #pragma unroll
        for (int ms = 0; ms < 4; ++ms)
            #pragma unroll
            for (int r = 0; r < 4; ++r) acc[ms][ns][r] += bv;
    }

    if (final_) {   // coalesced fp32 stores (16 lanes x 4B = 64B lines)
        #pragma unroll
        for (int ns = 0; ns < 2; ++ns) {
            int col = n0 + wn + ns * 16 + l15;
            #pragma unroll
            for (int ms = 0; ms < 4; ++ms)
                #pragma unroll
                for (int r = 0; r < 4; ++r)
                    Cf[(size_t)(m0 + wm + ms * 16 + quad * 4 + r) * 512 + col] = acc[ms][ns][r];
        }
        return;
    }

    const int h0 = n0 >> 6;
    const int b = m0 >> 11, rr0 = m0 & 2047;
    const int passes = (mi == 1) ? 1 : 2;
    for (int pass = 0; pass < passes; ++pass) {
        __syncthreads();
        // acc -> LDS (V: transposed [col][row], b64; Q/K: row-major [row][col], b16)
        #pragma unroll
        for (int ms = 0; ms < 4; ++ms) {
            #pragma unroll
            for (int ns = 0; ns < 2; ++ns) {
                int cl = wn + ns * 16 + l15;
                int rl = wm + ms * 16 + quad * 4;
                if (mi == 2) {
                    ushort4 w4;
                    #pragma unroll
                    for (int r = 0; r < 4; ++r) {
                        ushort h, l; splitbf(acc[ms][ns][r], h, l);
                        ((ushort*)&w4)[r] = pass ? l : h;
                    }
                    *(ushort4*)&gs.E[cl * 136 + rl] = w4;
                } else {
                    #pragma unroll
                    for (int r = 0; r < 4; ++r) {
                        float v = acc[ms][ns][r];
                        ushort out;
                        if (mi == 1) out = rnebf(v);
                        else { ushort h, l; splitbf(v, h, l); out = pass ? l : h; }
                        gs.E[(rl + r) * 72 + cl] = out;
                    }
                }
            }
        }
        __syncthreads();
        // LDS -> global, wide coalesced uint4
        if (mi == 2) {
            ushort* dst = pass ? VlT : VhT;
            #pragma unroll
            for (int i = 0; i < 4; ++i) {
                int idx = tid + i * 256;
                int d = idx >> 4, rg = idx & 15;
                uint4 u = *(const uint4*)&gs.E[d * 136 + rg * 8];
                *(uint4*)&dst[((size_t)(b * 8 + h0) * 64 + d) * 2048 + rr0 + rg * 8] = u;
            }
        } else {
            ushort* dst = (mi == 0) ? (pass ? Ql : Qh) : Khp;
            #pragma unroll
            for (int i = 0; i < 4; ++i) {
                int idx = tid + i * 256;
                int row = idx >> 3, cg = idx & 7;
                uint4 u = *(const uint4*)&gs.E[row * 72 + cg * 8];
                *(uint4*)&dst[((size_t)(b * 8 + h0) * 2048 + rr0 + row) * 64 + cg * 8] = u;
            }
        }
    }
}

// ---- Flash attention, S^T dataflow, in-block split-K, async dbuf, 512 threads ----
union SmemU {
    struct { ushort KVs[2][6][4096]; ushort Pp[8][64 * LDP2]; } p1;
    struct { float Obuf[4][64 * 68]; float Lbuf[4][64]; } p2;
};

__global__ __launch_bounds__(512, 2) void attn3_kernel(
    const ushort* __restrict__ Qh, const ushort* __restrict__ Ql,
    const ushort* __restrict__ Kh, const ushort* __restrict__ VhT,
    const ushort* __restrict__ VlT, const int* __restrict__ mask,
    float* __restrict__ XS)
{
    __shared__ SmemU smem;
    const int tid = threadIdx.x;
    const int wave = tid >> 6, lane = tid & 63;
    const int l15 = lane & 15, quad = lane >> 4;
    const int w4 = wave & 3, half = wave >> 2;
    const int bh = blockIdx.x, b = bh >> 3, h = bh & 7;
    const int q0 = blockIdx.y * 256;

    bf16x8 qh[4][2], ql[4][2];
    #pragma unroll
    for (int qs = 0; qs < 4; ++qs) {
        size_t qb = ((size_t)bh * 2048 + q0 + w4 * 64 + qs * 16 + l15) * 64 + quad * 8;
        qh[qs][0] = *(const bf16x8*)(Qh + qb);
        qh[qs][1] = *(const bf16x8*)(Qh + qb + 32);
        ql[qs][0] = *(const bf16x8*)(Ql + qb);
        ql[qs][1] = *(const bf16x8*)(Ql + qb + 32);
    }

    const f32x4 z = {0.f, 0.f, 0.f, 0.f};
    f32x4 oacc[4][4];
    #pragma unroll
    for (int i = 0; i < 4; ++i)
        #pragma unroll
        for (int j = 0; j < 4; ++j) oacc[i][j] = z;
    float lacc[4] = {0.f, 0.f, 0.f, 0.f};

    const int rloc = lane >> 3, gs = (lane & 7) ^ rloc;
    const ushort* sb[6]; size_t sstep[6]; int dofs[6];
    #pragma unroll
    for (int i = 0; i < 6; ++i) {
        int cc = wave * 6 + i;
        int hc = cc / 24, r24 = cc % 24, pc = r24 >> 3, ic = r24 & 7;
        if (pc == 0) {
            sb[i] = Kh + ((size_t)(bh * 2048 + hc * 1024 + ic * 8 + rloc)) * 64 + gs * 8;
            sstep[i] = (size_t)64 * 64;
        } else {
            const ushort* vp = (pc == 1) ? VhT : VlT;
            sb[i] = vp + ((size_t)(bh * 64 + ic * 8 + rloc)) * 2048 + hc * 1024 + gs * 8;
            sstep[i] = 64;
        }
        dofs[i] = (hc * 3 + pc) * 4096 + ic * 512;
    }

    const int sw0 = (quad ^ (l15 & 7)) * 8;
    const int mrow0 = b * 2048 + half * 1024;

    #pragma unroll
    for (int i = 0; i < 6; ++i)
        async16(sb[i], &smem.p1.KVs[0][0][0] + dofs[i]);

    for (int t = 0; t < 16; ++t) {
        __syncthreads();
        if (t < 15) {
            #pragma unroll
            for (int i = 0; i < 6; ++i)
                async16(sb[i] + (size_t)(t + 1) * sstep[i], &smem.p1.KVs[(t + 1) & 1][0][0] + dofs[i]);
        }
        const int p = t & 1;
        const ushort* K0 = smem.p1.KVs[p][half * 3 + 0];
        const ushort* V0 = smem.p1.KVs[p][half * 3 + 1];
        const ushort* V1 = smem.p1.KVs[p][half * 3 + 2];
        ushort* Pw = smem.p1.Pp[wave];

        #pragma unroll
        for (int ks = 0; ks < 2; ++ks) {
            #pragma unroll
            for (int kt2 = 0; kt2 < 2; ++kt2) {
                const int kt = ks * 2 + kt2;
                const int kb = (kt * 16 + l15) * 64;
                bf16x8 ka0 = *(const bf16x8*)&K0[kb + sw0];
                bf16x8 ka1 = *(const bf16x8*)&K0[kb + (sw0 ^ 32)];
                int4 mv = *(const int4*)(mask + mrow0 + t * 64 + kt * 16 + quad * 4);
                float bias[4];
                bias[0] = mv.x ? 0.f : -1e30f; bias[1] = mv.y ? 0.f : -1e30f;
                bias[2] = mv.z ? 0.f : -1e30f; bias[3] = mv.w ? 0.f : -1e30f;
                #pragma unroll
                for (int qs = 0; qs < 4; ++qs) {
                    f32x4 a = z;
                    a = MFMA16(ka0, ql[qs][0], a);
                    a = MFMA16(ka1, ql[qs][1], a);
                    a = MFMA16(ka0, qh[qs][0], a);
                    a = MFMA16(ka1, qh[qs][1], a);
                    ushort4 hv;
                    #pragma unroll
                    for (int r = 0; r < 4; ++r) {
                        float pv = __expf(a[r] * 0.125f + bias[r]);
                        unsigned u = __float_as_uint(pv);
                        unsigned hu = (u + 0x7fffu + ((u >> 16) & 1u)) & 0xffff0000u;
                        lacc[qs] += __uint_as_float(hu);
                        ((ushort*)&hv)[r] = (ushort)(hu >> 16);
                    }
                    *(ushort4*)&Pw[(qs * 16 + l15) * LDP2 + kt2 * 16 + quad * 4] = hv;
                }
            }
            const int svo = sw0 ^ (ks * 32);
            bf16x8 pf[4];
            #pragma unroll
            for (int qs = 0; qs < 4; ++qs)
                pf[qs] = *(const bf16x8*)&Pw[(qs * 16 + l15) * LDP2 + quad * 8];
            #pragma unroll
            for (int dsub = 0; dsub < 4; ++dsub) {
                const int vb = (dsub * 16 + l15) * 64;
                bf16x8 vh = *(const bf16x8*)&V0[vb + svo];
                bf16x8 vl = *(const bf16x8*)&V1[vb + svo];
                #pragma unroll
                for (int qs = 0; qs < 4; ++qs) {
                    oacc[qs][dsub] = MFMA16(vl, pf[qs], oacc[qs][dsub]);
                    oacc[qs][dsub] = MFMA16(vh, pf[qs], oacc[qs][dsub]);
                }
            }
        }
    }

    float lv[4];
    #pragma unroll
    for (int qs = 0; qs < 4; ++qs) {
        float v = lacc[qs];
        v += __shfl_xor(v, 16);
        v += __shfl_xor(v, 32);
        lv[qs] = v;
    }

    __syncthreads();
    if (half == 1) {
        #pragma unroll
        for (int qs = 0; qs < 4; ++qs) {
            #pragma unroll
            for (int dsub = 0; dsub < 4; ++dsub) {
                float4 o4 = {oacc[qs][dsub][0], oacc[qs][dsub][1], oacc[qs][dsub][2], oacc[qs][dsub][3]};
                *(float4*)&smem.p2.Obuf[w4][(qs * 16 + l15) * 68 + dsub * 16 + quad * 4] = o4;
            }
            if (quad == 0) smem.p2.Lbuf[w4][qs * 16 + l15] = lv[qs];
        }
    }
    __syncthreads();
    if (half == 0) {
        #pragma unroll
        for (int qs = 0; qs < 4; ++qs) {
            float ltot = lv[qs] + smem.p2.Lbuf[w4][qs * 16 + l15];
            float inv = (ltot > 0.f) ? 1.f / ltot : 0.f;
            int row = q0 + w4 * 64 + qs * 16 + l15;
            float* rowp = XS + ((size_t)(b * 2048 + row)) * 512 + h * 64;
            #pragma unroll
            for (int dsub = 0; dsub < 4; ++dsub) {
                float4 p4 = *(const float4*)&smem.p2.Obuf[w4][(qs * 16 + l15) * 68 + dsub * 16 + quad * 4];
                float4 o4;
                o4.x = (oacc[qs][dsub][0] + p4.x) * inv;
                o4.y = (oacc[qs][dsub][1] + p4.y) * inv;
                o4.z = (oacc[qs][dsub][2] + p4.z) * inv;
                o4.w = (oacc[qs][dsub][3] + p4.w) * inv;
                *(float4*)(rowp + dsub * 16 + quad * 4) = o4;
            }
        }
    }
}

extern "C" void kernel_launch(void* const* d_in, const int* in_sizes, int n_in,
                              void* d_out, int out_size, void* d_ws, size_t ws_size,
                              hipStream_t stream) {
    const float* query = (const float*)d_in[0];
    const float* key   = (const float*)d_in[1];
    const float* value = (const float*)d_in[2];
    const int*   mask  = (const int*)d_in[3];
    const float* Wq = (const float*)d_in[4];
    const float* bq = (const float*)d_in[5];
    const float* Wk = (const float*)d_in[6];
    const float* bk = (const float*)d_in[7];
    const float* Wv = (const float*)d_in[8];
    const float* bv = (const float*)d_in[9];
    const float* Wo = (const float*)d_in[10];
    const float* bo = (const float*)d_in[11];

    char* w = (char*)d_ws;
    const size_t MB = (size_t)1 << 20;
    ushort* Qh  = (ushort*)(w + 0 * MB);
    ushort* Ql  = (ushort*)(w + 8 * MB);
    ushort* Khp = (ushort*)(w + 16 * MB);
    ushort* VhT = (ushort*)(w + 24 * MB);
    ushort* VlT = (ushort*)(w + 32 * MB);
    float*  XS  = (float*)(w + 40 * MB);          // 16 MB fp32
    ushort* WTh = (ushort*)(w + 56 * MB);          // [1536][512]
    ushort* WTl = WTh + (size_t)1536 * 512;
    // Wo planes reuse the Qh region (dead after attn3)
    ushort* WoTh = (ushort*)(w + 0 * MB);
    ushort* WoTl = WoTh + (size_t)512 * 512;

    wsplit3_kernel<<<dim3(8, 8, 3), 256, 0, stream>>>(Wq, Wk, Wv, WTh, WTl);
    gemm2_kernel<<<dim3(64, 24), 256, 0, stream>>>(
        query, key, value, WTh, WTl, bq, bk, bv, 0, nullptr, Qh, Ql, Khp, VhT, VlT);
    attn3_kernel<<<dim3(32, 8), 512, 0, stream>>>(Qh, Ql, Khp, VhT, VlT, mask, XS);
    wsplit3_kernel<<<dim3(8, 8, 1), 256, 0, stream>>>(Wo, Wo, Wo, WoTh, WoTl);
    gemm2_kernel<<<dim3(64, 8), 256, 0, stream>>>(
        XS, XS, XS, WoTh, WoTl, bo, bo, bo, 1, (float*)d_out,
        nullptr, nullptr, nullptr, nullptr, nullptr);
}